// Round 3
// baseline (58.633 us; speedup 1.0000x reference)
//
#include <hip/hip_runtime.h>
#include <math.h>

#define N_STATIONS 276
#define CTX4 96            // float4s per z row
#define TGT 96
#define BATCH 4096
#define TILE 16            // samples per block tile
#define NT 6               // tiles per station (covers m<=96; last tile loops anyway)
#define R 3                // rows per 16-lane group
#define ROWS_PER_BLOCK 48  // TGT / 2
#define LDS_ROW_F4 97      // 96 + 1 float4 pad

// ---------- kernel 1: build per-station sample lists ----------
__global__ __launch_bounds__(1024) void build_lists(
    const int* __restrict__ stations,
    int* __restrict__ order,    // (BATCH,)
    int* __restrict__ offsets)  // (N_STATIONS+1,)
{
    __shared__ int cnt[N_STATIONS];
    __shared__ int off[N_STATIONS + 1];
    const int tid = threadIdx.x;
    for (int i = tid; i < N_STATIONS; i += 1024) cnt[i] = 0;
    __syncthreads();
    for (int b = tid; b < BATCH; b += 1024) atomicAdd(&cnt[stations[b]], 1);
    __syncthreads();
    if (tid <= N_STATIONS) {
        int acc = 0;
        for (int i = 0; i < tid; ++i) acc += cnt[i];
        off[tid] = acc;
    }
    __syncthreads();
    for (int i = tid; i < N_STATIONS; i += 1024) cnt[i] = 0;
    __syncthreads();
    for (int b = tid; b < BATCH; b += 1024) {
        int s = stations[b];
        int p = atomicAdd(&cnt[s], 1);
        order[off[s] + p] = b;    // unordered within station: values don't depend on order
    }
    if (tid <= N_STATIONS) offsets[tid] = off[tid];
}

// ---------- kernel 2: tiled grouped GEMV ----------
// grid = (NT*2, N_STATIONS); block = 256 (16 groups x 16 lanes)
__global__ __launch_bounds__(256) void nlinear_tiled(
    const float* __restrict__ z,        // (BATCH, CTX)
    const int*   __restrict__ order,
    const int*   __restrict__ offsets,
    const float* __restrict__ W,        // (N_STATIONS, TGT, CTX)
    const float* __restrict__ bias,     // (N_STATIONS, TGT)
    const float* __restrict__ loc,
    const float* __restrict__ scale,
    float*       __restrict__ out)      // (BATCH, TGT)
{
    const int s    = blockIdx.y;
    const int tile = blockIdx.x >> 1;
    const int h    = blockIdx.x & 1;

    const int start = offsets[s];
    const int end   = offsets[s + 1];
    const int j0    = start + tile * TILE;
    if (j0 >= end) return;
    int jend = j0 + TILE;
    if (tile == NT - 1 || jend > end) jend = end;   // last tile absorbs any overflow

    __shared__ float4 zn[TILE * LDS_ROW_F4];
    __shared__ int list[TILE];

    const int tid = threadIdx.x;
    const int t   = tid & 15;
    const int grp = tid >> 4;

    // W rows -> registers (read once per block)
    const int row0 = h * ROWS_PER_BLOCK + grp * R;
    const float4* w4 = reinterpret_cast<const float4*>(W) + ((size_t)s * TGT + row0) * CTX4;
    float4 wr[R][6];
#pragma unroll
    for (int r = 0; r < R; ++r)
#pragma unroll
        for (int k = 0; k < 6; ++k)
            wr[r][k] = w4[(size_t)r * CTX4 + t + 16 * k];

    const float lc  = loc[s];
    const float sc  = scale[s];
    const float inv = 1.0f / sc;
    float br[R];
#pragma unroll
    for (int r = 0; r < R; ++r) br[r] = bias[(size_t)s * TGT + row0 + r];

    const float4* z4 = reinterpret_cast<const float4*>(z);

    for (int c0 = j0; c0 < jend; c0 += TILE) {
        int mch = jend - c0; if (mch > TILE) mch = TILE;
        if (c0 > j0) __syncthreads();
        if (tid < mch) list[tid] = order[c0 + tid];
        // stage normalized z rows (order[] read direct from L2; broadcast-cheap)
        for (int idx = tid; idx < mch * CTX4; idx += 256) {
            int j = idx / CTX4;
            int q = idx - j * CTX4;
            float4 v = z4[(size_t)order[c0 + j] * CTX4 + q];
            float4 vn;
            vn.x = (v.x - lc) * inv;
            vn.y = (v.y - lc) * inv;
            vn.z = (v.z - lc) * inv;
            vn.w = (v.w - lc) * inv;
            zn[j * LDS_ROW_F4 + q] = vn;
        }
        __syncthreads();

        for (int jt = 0; jt < mch; jt += 2) {
            const int j1 = (jt + 1 < mch) ? jt + 1 : jt;
            float4 za[6], zb[6];
#pragma unroll
            for (int k = 0; k < 6; ++k) {
                za[k] = zn[jt * LDS_ROW_F4 + t + 16 * k];
                zb[k] = zn[j1 * LDS_ROW_F4 + t + 16 * k];
            }
            float accA[R], accB[R];
#pragma unroll
            for (int r = 0; r < R; ++r) {
                float a0 = 0.f, a1 = 0.f;
#pragma unroll
                for (int k = 0; k < 6; ++k) {
                    a0 += wr[r][k].x * za[k].x + wr[r][k].y * za[k].y
                        + wr[r][k].z * za[k].z + wr[r][k].w * za[k].w;
                    a1 += wr[r][k].x * zb[k].x + wr[r][k].y * zb[k].y
                        + wr[r][k].z * zb[k].z + wr[r][k].w * zb[k].w;
                }
                accA[r] = a0; accB[r] = a1;
            }
#pragma unroll
            for (int off = 8; off > 0; off >>= 1) {
#pragma unroll
                for (int r = 0; r < R; ++r) {
                    accA[r] += __shfl_xor(accA[r], off, 64);
                    accB[r] += __shfl_xor(accB[r], off, 64);
                }
            }
            const bool wA = (t == 0);
            const bool wB = (t == 8) && (jt + 1 < mch);
            if (wA || wB) {
                const int jj = wB ? j1 : jt;
                const int b  = list[jj];
                float* op = out + (size_t)b * TGT + row0;
#pragma unroll
                for (int r = 0; r < R; ++r) {
                    float v = wB ? accB[r] : accA[r];
                    v = (v + br[r]) * sc + lc;
                    op[r] = fmaxf(v, 0.f) + log1pf(expf(-fabsf(v)));
                }
            }
        }
    }
}

extern "C" void kernel_launch(void* const* d_in, const int* in_sizes, int n_in,
                              void* d_out, int out_size, void* d_ws, size_t ws_size,
                              hipStream_t stream) {
    const float* z        = (const float*)d_in[0];
    const int*   stations = (const int*)  d_in[1];
    const float* W        = (const float*)d_in[2];
    const float* bias     = (const float*)d_in[3];
    const float* loc      = (const float*)d_in[4];
    const float* scale    = (const float*)d_in[5];
    float* out = (float*)d_out;

    int* order   = (int*)d_ws;
    int* offsets = order + BATCH;

    build_lists<<<1, 1024, 0, stream>>>(stations, order, offsets);
    dim3 grid(NT * 2, N_STATIONS);
    nlinear_tiled<<<grid, 256, 0, stream>>>(z, order, offsets, W, bias, loc, scale, out);
}

// Round 4
// 34.913 us; speedup vs baseline: 1.6794x; 1.6794x over previous
//
#include <hip/hip_runtime.h>
#include <math.h>

#define N_STATIONS 276
#define CTX4 96            // float4s per z row
#define TGT 96
#define BATCH 4096

#define SLOTS_MAX (BATCH + N_STATIONS)   // even-padded list slots: 4372
#define NWG 2192                          // >= ceil(SLOTS_MAX/2), multiple of 8
#define CPX (NWG / 8)                     // 274 blocks per XCD chunk

// ---------- kernel 1: per-station lists, padded to even length ----------
// ws layout: ws[0] = npairs; ws[1..1+SLOTS_MAX) = order (sample ids, -1 = pad)
__global__ __launch_bounds__(1024) void build_pairs(
    const int* __restrict__ stations,
    int* __restrict__ ws)
{
    __shared__ int cnt[N_STATIONS];
    __shared__ int cnt2[N_STATIONS];
    __shared__ int poff[N_STATIONS + 1];
    const int tid = threadIdx.x;
    for (int i = tid; i < N_STATIONS; i += 1024) { cnt[i] = 0; cnt2[i] = 0; }
    __syncthreads();
    for (int b = tid; b < BATCH; b += 1024) atomicAdd(&cnt[stations[b]], 1);
    __syncthreads();
    if (tid <= N_STATIONS) {             // parallel quadratic prefix over 277 entries
        int acc = 0;
        for (int i = 0; i < tid; ++i) acc += (cnt[i] + 1) & ~1;  // even-ceil
        poff[tid] = acc;
    }
    __syncthreads();
    int* order = ws + 1;
    for (int b = tid; b < BATCH; b += 1024) {
        int s = stations[b];
        int p = atomicAdd(&cnt2[s], 1);
        order[poff[s] + p] = b;          // within-station order irrelevant to output values
    }
    for (int s = tid; s < N_STATIONS; s += 1024)
        if (cnt[s] & 1) order[poff[s] + cnt[s]] = -1;   // disjoint slot, no sync needed
    if (tid == 0) ws[0] = poff[N_STATIONS] / 2;
}

// ---------- kernel 2: one block per same-station sample pair ----------
// 256 thr = 16 groups x 16 lanes; group g computes rows g*6..g*6+5 for both samples.
// W rows streamed through registers (L2-served via XCD swizzle); z in registers.
__global__ __launch_bounds__(256, 4) void nlinear_pairs(
    const float* __restrict__ z,        // (BATCH, CTX)
    const int*   __restrict__ stations,
    const float* __restrict__ W,        // (N_STATIONS, TGT, CTX)
    const float* __restrict__ bias,     // (N_STATIONS, TGT)
    const float* __restrict__ loc,
    const float* __restrict__ scale,
    const int*   __restrict__ ws,
    float*       __restrict__ out)      // (BATCH, TGT)
{
    // XCD swizzle: consecutive qids (same station) land on the same XCD's L2
    const int bid = blockIdx.x;
    const int qid = (bid & 7) * CPX + (bid >> 3);
    const int npairs = ws[0];
    if (qid >= npairs) return;

    const int* order = ws + 1;
    const int i0 = order[qid * 2];
    int i1 = order[qid * 2 + 1];
    const bool v1 = (i1 >= 0);
    if (!v1) i1 = i0;                   // pad: recompute sample 0, guard the store

    const int s = stations[i0];
    const float lc = loc[s], sc = scale[s], inv = 1.0f / sc;

    const int tid = threadIdx.x;
    const int t   = tid & 15;
    const int grp = tid >> 4;

    // normalized z rows -> registers (lane t owns float4s {t, t+16, ..., t+80})
    const float4* z4 = reinterpret_cast<const float4*>(z);
    float4 za[6], zb[6];
#pragma unroll
    for (int k = 0; k < 6; ++k) {
        float4 a = z4[(size_t)i0 * CTX4 + t + 16 * k];
        float4 b = z4[(size_t)i1 * CTX4 + t + 16 * k];
        za[k].x = (a.x - lc) * inv; za[k].y = (a.y - lc) * inv;
        za[k].z = (a.z - lc) * inv; za[k].w = (a.w - lc) * inv;
        zb[k].x = (b.x - lc) * inv; zb[k].y = (b.y - lc) * inv;
        zb[k].z = (b.z - lc) * inv; zb[k].w = (b.w - lc) * inv;
    }

    const float4* w4 = reinterpret_cast<const float4*>(W) + (size_t)s * TGT * CTX4;

#pragma unroll 2
    for (int r = 0; r < 6; ++r) {
        const int row = grp * 6 + r;
        const float4* wr = w4 + (size_t)row * CTX4;
        float4 aA = {0.f, 0.f, 0.f, 0.f}, aB = {0.f, 0.f, 0.f, 0.f};
#pragma unroll
        for (int k = 0; k < 6; ++k) {
            float4 w = wr[t + 16 * k];
            aA.x += w.x * za[k].x; aA.y += w.y * za[k].y;
            aA.z += w.z * za[k].z; aA.w += w.w * za[k].w;
            aB.x += w.x * zb[k].x; aB.y += w.y * zb[k].y;
            aB.z += w.z * zb[k].z; aB.w += w.w * zb[k].w;
        }
        float sA = (aA.x + aA.y) + (aA.z + aA.w);
        float sB = (aB.x + aB.y) + (aB.z + aB.w);
#pragma unroll
        for (int off = 8; off > 0; off >>= 1) {
            sA += __shfl_xor(sA, off, 64);
            sB += __shfl_xor(sB, off, 64);
        }
        if (t == 0 || (t == 1 && v1)) {
            const int   id = (t == 0) ? i0 : i1;
            const float sv = (t == 0) ? sA : sB;
            float v = (sv + bias[(size_t)s * TGT + row]) * sc + lc;
            out[(size_t)id * TGT + row] = fmaxf(v, 0.f) + log1pf(expf(-fabsf(v)));
        }
    }
}

extern "C" void kernel_launch(void* const* d_in, const int* in_sizes, int n_in,
                              void* d_out, int out_size, void* d_ws, size_t ws_size,
                              hipStream_t stream) {
    const float* z        = (const float*)d_in[0];
    const int*   stations = (const int*)  d_in[1];
    const float* W        = (const float*)d_in[2];
    const float* bias     = (const float*)d_in[3];
    const float* loc      = (const float*)d_in[4];
    const float* scale    = (const float*)d_in[5];
    float* out = (float*)d_out;
    int* ws = (int*)d_ws;

    build_pairs<<<1, 1024, 0, stream>>>(stations, ws);
    nlinear_pairs<<<NWG, 256, 0, stream>>>(z, stations, W, bias, loc, scale, ws, out);
}

// Round 5
// 33.512 us; speedup vs baseline: 1.7496x; 1.0418x over previous
//
#include <hip/hip_runtime.h>
#include <math.h>

#define N_STATIONS 276
#define CTX4 96            // float4s per z row
#define TGT 96
#define BATCH 4096

#define SLOTS_MAX (BATCH + 3 * N_STATIONS)   // quad-padded list slots: 4924
#define NWG 1232                              // >= ceil(SLOTS_MAX/4)=1231, multiple of 8
#define CPX (NWG / 8)                         // 154 blocks per XCD chunk

// ---------- kernel 1: per-station lists, padded to multiple of 4 ----------
// ws layout: ws[0] = nquads; ws[1..1+SLOTS_MAX) = order (sample ids, -1 = pad)
__global__ __launch_bounds__(1024) void build_quads(
    const int* __restrict__ stations,
    int* __restrict__ ws)
{
    __shared__ int cnt[N_STATIONS];
    __shared__ int cnt2[N_STATIONS];
    __shared__ int poff[N_STATIONS + 1];
    const int tid = threadIdx.x;
    for (int i = tid; i < N_STATIONS; i += 1024) { cnt[i] = 0; cnt2[i] = 0; }
    __syncthreads();
    for (int b = tid; b < BATCH; b += 1024) atomicAdd(&cnt[stations[b]], 1);
    __syncthreads();
    if (tid <= N_STATIONS) {             // parallel quadratic prefix over 277 entries
        int acc = 0;
        for (int i = 0; i < tid; ++i) acc += (cnt[i] + 3) & ~3;  // quad-ceil
        poff[tid] = acc;
    }
    __syncthreads();
    int* order = ws + 1;
    for (int b = tid; b < BATCH; b += 1024) {
        int s = stations[b];
        int p = atomicAdd(&cnt2[s], 1);
        order[poff[s] + p] = b;          // within-station order irrelevant to output values
    }
    for (int s = tid; s < N_STATIONS; s += 1024) {
        int c = cnt[s], e = (c + 3) & ~3;
        for (int j = c; j < e; ++j) order[poff[s] + j] = -1;  // disjoint slots, no sync needed
    }
    if (tid == 0) ws[0] = poff[N_STATIONS] / 4;
}

// ---------- kernel 2: one block per same-station sample QUAD ----------
// 256 thr = 16 groups x 16 lanes; group g computes rows g*6..g*6+5 for 4 samples.
// W rows streamed through registers (L2-served via XCD swizzle); z in registers.
__global__ __launch_bounds__(256) void nlinear_quads(
    const float* __restrict__ z,        // (BATCH, CTX)
    const int*   __restrict__ stations,
    const float* __restrict__ W,        // (N_STATIONS, TGT, CTX)
    const float* __restrict__ bias,     // (N_STATIONS, TGT)
    const float* __restrict__ loc,
    const float* __restrict__ scale,
    const int*   __restrict__ ws,
    float*       __restrict__ out)      // (BATCH, TGT)
{
    // XCD swizzle: consecutive qids (same station) land on the same XCD's L2
    const int bid = blockIdx.x;
    const int qid = (bid & 7) * CPX + (bid >> 3);
    const int nquads = ws[0];
    if (qid >= nquads) return;

    const int* order = ws + 1;
    const int i0 = order[qid * 4];
    int i1 = order[qid * 4 + 1];
    int i2 = order[qid * 4 + 2];
    int i3 = order[qid * 4 + 3];
    const bool v1 = (i1 >= 0), v2 = (i2 >= 0), v3 = (i3 >= 0);
    if (!v1) i1 = i0;
    if (!v2) i2 = i0;
    if (!v3) i3 = i0;

    const int s = stations[i0];
    const float lc = loc[s], sc = scale[s], inv = 1.0f / sc;

    const int tid = threadIdx.x;
    const int t   = tid & 15;
    const int grp = tid >> 4;

    // normalized z rows -> registers (lane t owns float4s {t, t+16, ..., t+80})
    const float4* z4 = reinterpret_cast<const float4*>(z);
    float4 z0[6], z1[6], z2[6], z3[6];
#pragma unroll
    for (int k = 0; k < 6; ++k) {
        float4 a = z4[(size_t)i0 * CTX4 + t + 16 * k];
        float4 b = z4[(size_t)i1 * CTX4 + t + 16 * k];
        float4 c = z4[(size_t)i2 * CTX4 + t + 16 * k];
        float4 d = z4[(size_t)i3 * CTX4 + t + 16 * k];
        z0[k].x = (a.x - lc) * inv; z0[k].y = (a.y - lc) * inv;
        z0[k].z = (a.z - lc) * inv; z0[k].w = (a.w - lc) * inv;
        z1[k].x = (b.x - lc) * inv; z1[k].y = (b.y - lc) * inv;
        z1[k].z = (b.z - lc) * inv; z1[k].w = (b.w - lc) * inv;
        z2[k].x = (c.x - lc) * inv; z2[k].y = (c.y - lc) * inv;
        z2[k].z = (c.z - lc) * inv; z2[k].w = (c.w - lc) * inv;
        z3[k].x = (d.x - lc) * inv; z3[k].y = (d.y - lc) * inv;
        z3[k].z = (d.z - lc) * inv; z3[k].w = (d.w - lc) * inv;
    }

    const float4* w4 = reinterpret_cast<const float4*>(W) + (size_t)s * TGT * CTX4;

    for (int r = 0; r < 6; ++r) {
        const int row = grp * 6 + r;
        const float4* wr = w4 + (size_t)row * CTX4;
        float4 a0 = {0,0,0,0}, a1 = {0,0,0,0}, a2 = {0,0,0,0}, a3 = {0,0,0,0};
#pragma unroll
        for (int k = 0; k < 6; ++k) {
            float4 w = wr[t + 16 * k];
            a0.x += w.x * z0[k].x; a0.y += w.y * z0[k].y;
            a0.z += w.z * z0[k].z; a0.w += w.w * z0[k].w;
            a1.x += w.x * z1[k].x; a1.y += w.y * z1[k].y;
            a1.z += w.z * z1[k].z; a1.w += w.w * z1[k].w;
            a2.x += w.x * z2[k].x; a2.y += w.y * z2[k].y;
            a2.z += w.z * z2[k].z; a2.w += w.w * z2[k].w;
            a3.x += w.x * z3[k].x; a3.y += w.y * z3[k].y;
            a3.z += w.z * z3[k].z; a3.w += w.w * z3[k].w;
        }
        float s0 = (a0.x + a0.y) + (a0.z + a0.w);
        float s1 = (a1.x + a1.y) + (a1.z + a1.w);
        float s2 = (a2.x + a2.y) + (a2.z + a2.w);
        float s3 = (a3.x + a3.y) + (a3.z + a3.w);
#pragma unroll
        for (int off = 8; off > 0; off >>= 1) {
            s0 += __shfl_xor(s0, off, 64);
            s1 += __shfl_xor(s1, off, 64);
            s2 += __shfl_xor(s2, off, 64);
            s3 += __shfl_xor(s3, off, 64);
        }
        // lanes 0..3 write samples 0..3 (guarded for pads)
        const bool wv = (t == 0) || (t == 1 && v1) || (t == 2 && v2) || (t == 3 && v3);
        if (wv) {
            const int   id = (t == 0) ? i0 : (t == 1) ? i1 : (t == 2) ? i2 : i3;
            const float sv = (t == 0) ? s0 : (t == 1) ? s1 : (t == 2) ? s2 : s3;
            float v = (sv + bias[(size_t)s * TGT + row]) * sc + lc;
            out[(size_t)id * TGT + row] = fmaxf(v, 0.f) + log1pf(expf(-fabsf(v)));
        }
    }
}

extern "C" void kernel_launch(void* const* d_in, const int* in_sizes, int n_in,
                              void* d_out, int out_size, void* d_ws, size_t ws_size,
                              hipStream_t stream) {
    const float* z        = (const float*)d_in[0];
    const int*   stations = (const int*)  d_in[1];
    const float* W        = (const float*)d_in[2];
    const float* bias     = (const float*)d_in[3];
    const float* loc      = (const float*)d_in[4];
    const float* scale    = (const float*)d_in[5];
    float* out = (float*)d_out;
    int* ws = (int*)d_ws;

    build_quads<<<1, 1024, 0, stream>>>(stations, ws);
    nlinear_quads<<<NWG, 256, 0, stream>>>(z, stations, W, bias, loc, scale, ws, out);
}